// Round 3
// baseline (1773.217 us; speedup 1.0000x reference)
//
#include <hip/hip_runtime.h>
#include <hip/hip_bf16.h>

#define N_NODES 100000
#define N_EDGES 3200000
#define F_IN 512
#define NHEAD 8
#define CH1 8
#define F1 64   // NHEAD*CH1
#define C2 7
#define NEG 0.2f

typedef __bf16 bf16x8 __attribute__((ext_vector_type(8)));
typedef float  f32x4  __attribute__((ext_vector_type(4)));
typedef unsigned int u32x4 __attribute__((ext_vector_type(4)));

union U4BF8 { u32x4 u; bf16x8 v; };

// load element i of a buffer whose dtype is f32 (mode=1) or bf16 (mode=0)
__device__ __forceinline__ float ldmix(const void* p, size_t i, int f32mode) {
  if (f32mode) return ((const float*)p)[i];
  union { unsigned short u; __bf16 b; } c;
  c.u = ((const unsigned short*)p)[i];
  return (float)c.b;
}

// ---------------- dtype detection: 1 wave -----------------------------------
// f32 data read as bf16: low 16 bits of each dword are raw mantissa bits ->
// random exponent -> some |v|>1e6 or NaN among 64 samples (P_miss ~ 6e-16).
// true bf16 data: low half = actual Gaussian x value, |v| <= ~6.
__global__ void detect_kernel(const unsigned int* __restrict__ x, int* __restrict__ flag) {
  int lane = threadIdx.x & 63;
  unsigned int w = x[lane];
  union { unsigned short u; __bf16 b; } c;
  c.u = (unsigned short)(w & 0xFFFFu);
  float v = (float)c.b;
  bool big = !(fabsf(v) <= 1e6f);   // true for huge or NaN
  unsigned long long m = __ballot(big);
  if (lane == 0) *flag = (m != 0ull) ? 1 : 0;
}

// ---------------- GEMM: h1[N,64] = x[N,512] @ W1[512,64]  (bf16 out) -------
__global__ __launch_bounds__(256) void gemm1_kernel(
    const void* __restrict__ x, const void* __restrict__ W1,
    __bf16* __restrict__ h1, const int* __restrict__ flag)
{
  const int mode = *flag;
  const int lane = threadIdx.x & 63;
  const int wave = threadIdx.x >> 6;
  const int c0   = wave * 16;
  const int m    = lane & 15;
  const int quad = lane >> 4;

  // B fragments for all 16 k-steps: bfrag[t][j] = W1[32t+quad*8+j][c0+m]
  bf16x8 bfrag[16];
#pragma unroll
  for (int t = 0; t < 16; ++t) {
    bf16x8 tv;
#pragma unroll
    for (int j = 0; j < 8; ++j)
      tv[j] = (__bf16)ldmix(W1, (size_t)(32*t + quad*8 + j)*F1 + c0 + m, mode);
    bfrag[t] = tv;
  }

  const int rowBase = blockIdx.x * 128;
#pragma unroll 1
  for (int rt = 0; rt < 8; ++rt) {
    const int r0 = rowBase + rt*16;
    int rowA = r0 + m; if (rowA > N_NODES-1) rowA = N_NODES-1;
    f32x4 acc = {0.f, 0.f, 0.f, 0.f};
    if (mode) {
      const float* xpf = (const float*)x + (size_t)rowA * F_IN + quad*8;
#pragma unroll
      for (int t = 0; t < 16; ++t) {
        f32x4 lo = *(const f32x4*)(xpf + t*32);
        f32x4 hi = *(const f32x4*)(xpf + t*32 + 4);
        bf16x8 av;
#pragma unroll
        for (int j = 0; j < 4; ++j) { av[j] = (__bf16)lo[j]; av[4+j] = (__bf16)hi[j]; }
        acc = __builtin_amdgcn_mfma_f32_16x16x32_bf16(av, bfrag[t], acc, 0, 0, 0);
      }
    } else {
      const __bf16* xp = (const __bf16*)x + (size_t)rowA * F_IN + quad*8;
#pragma unroll
      for (int t = 0; t < 16; ++t) {
        U4BF8 a;
        a.u = *(const u32x4*)(xp + t*32);
        acc = __builtin_amdgcn_mfma_f32_16x16x32_bf16(a.v, bfrag[t], acc, 0, 0, 0);
      }
    }
#pragma unroll
    for (int j = 0; j < 4; ++j) {
      int row = r0 + quad*4 + j;
      if (row < N_NODES) h1[(size_t)row*F1 + c0 + m] = (__bf16)acc[j];
    }
  }
}

// ---------------- alpha_s1/alpha_d1 [N,8] ----------------------------------
__global__ __launch_bounds__(256) void alpha1_kernel(
    const __bf16* __restrict__ h1,
    const void* __restrict__ a_src, const void* __restrict__ a_dst,
    float* __restrict__ as, float* __restrict__ ad, const int* __restrict__ flag)
{
  const int mode = *flag;
  int i = blockIdx.x * 256 + threadIdx.x;   // n*8+h
  if (i >= N_NODES * NHEAD) return;
  int h = i & 7;
  const __bf16* hp = h1 + (size_t)(i >> 3) * F1 + h * CH1;
  float s = 0.f, d = 0.f;
#pragma unroll
  for (int c = 0; c < CH1; ++c) {
    float hv = (float)hp[c];
    s += hv * ldmix(a_src, h*CH1 + c, mode);
    d += hv * ldmix(a_dst, h*CH1 + c, mode);
  }
  as[i] = s; ad[i] = d;
}

// ---------------- layer-1 edge scatter: wave per edge ----------------------
__global__ __launch_bounds__(256) void edge1_kernel(
    const int* __restrict__ ei, const __bf16* __restrict__ h1,
    const float* __restrict__ as, const float* __restrict__ ad,
    float* __restrict__ num, float* __restrict__ den)
{
  const int lane = threadIdx.x & 63;
  long long eid = (long long)blockIdx.x * 4 + (threadIdx.x >> 6);
  if (eid >= (long long)N_EDGES + N_NODES) return;
  int src, dst;
  if (eid < N_EDGES) { src = ei[eid]; dst = ei[N_EDGES + eid]; }
  else { src = dst = (int)(eid - N_EDGES); }
  int h = lane >> 3;
  float e = as[src*NHEAD + h] + ad[dst*NHEAD + h];
  e = e > 0.f ? e : NEG * e;
  float w = __expf(e);
  float hv = (float)h1[(size_t)src*F1 + lane];
  atomicAdd(num + (size_t)dst*F1 + lane, hv * w);
  if ((lane & 7) == 0) atomicAdd(den + dst*NHEAD + h, w);
}

// ---------------- finalize layer 1 (in place on num) -----------------------
__global__ __launch_bounds__(256) void finalize1_kernel(
    float* __restrict__ num, const float* __restrict__ den,
    const void* __restrict__ b1, const int* __restrict__ flag)
{
  const int mode = *flag;
  long long i = (long long)blockIdx.x * 256 + threadIdx.x;
  if (i >= (long long)N_NODES * F1) return;
  int col = (int)(i & 63);
  int n   = (int)(i >> 6);
  float d = den[n*NHEAD + (col >> 3)];
  num[i] = num[i] / (d + 1e-16f) + ldmix(b1, col, mode);
}

// ---------------- h2 = h1out @ W2, alpha2 ----------------------------------
__global__ __launch_bounds__(256) void h2_kernel(
    const float* __restrict__ h1o, const void* __restrict__ W2,
    const void* __restrict__ a_src2, const void* __restrict__ a_dst2,
    float* __restrict__ h2, float* __restrict__ as2, float* __restrict__ ad2,
    const int* __restrict__ flag)
{
  const int mode = *flag;
  __shared__ float W2f[F1*C2];
  __shared__ float asw[C2], adw[C2];
  int t = threadIdx.x;
  for (int i = t; i < F1*C2; i += 256) W2f[i] = ldmix(W2, i, mode);
  if (t < C2) { asw[t] = ldmix(a_src2, t, mode); adw[t] = ldmix(a_dst2, t, mode); }
  __syncthreads();
  int n = blockIdx.x * 256 + t;
  if (n >= N_NODES) return;
  const float* row = h1o + (size_t)n * F1;
  float r[F1];
#pragma unroll
  for (int j = 0; j < F1/4; ++j) {
    f32x4 v = *(const f32x4*)(row + 4*j);
    r[4*j] = v.x; r[4*j+1] = v.y; r[4*j+2] = v.z; r[4*j+3] = v.w;
  }
  float s = 0.f, d = 0.f;
#pragma unroll
  for (int c = 0; c < C2; ++c) {
    float acc = 0.f;
#pragma unroll
    for (int j = 0; j < F1; ++j) acc += r[j] * W2f[j*C2 + c];
    h2[(size_t)n*C2 + c] = acc;
    s += acc * asw[c]; d += acc * adw[c];
  }
  as2[n] = s; ad2[n] = d;
}

// ---------------- layer-2 edge scatter: 8 lanes per edge -------------------
__global__ __launch_bounds__(256) void edge2_kernel(
    const int* __restrict__ ei, const float* __restrict__ h2,
    const float* __restrict__ as2, const float* __restrict__ ad2,
    float* __restrict__ num2, float* __restrict__ den2)
{
  long long gid = (long long)blockIdx.x * 256 + threadIdx.x;
  long long eid = gid >> 3;
  int sub = (int)(gid & 7);
  if (eid >= (long long)N_EDGES + N_NODES) return;
  int src, dst;
  if (eid < N_EDGES) { src = ei[eid]; dst = ei[N_EDGES + eid]; }
  else { src = dst = (int)(eid - N_EDGES); }
  float e = as2[src] + ad2[dst];
  e = e > 0.f ? e : NEG * e;
  float w = __expf(e);
  if (sub < C2) atomicAdd(num2 + (size_t)dst*C2 + sub, h2[(size_t)src*C2 + sub] * w);
  else          atomicAdd(den2 + dst, w);
}

// ---------------- final: divide + bias + log_softmax -> out ----------------
__global__ __launch_bounds__(256) void out_kernel(
    const float* __restrict__ num2, const float* __restrict__ den2,
    const void* __restrict__ b2, void* __restrict__ out, const int* __restrict__ flag)
{
  const int mode = *flag;
  int n = blockIdx.x * 256 + threadIdx.x;
  if (n >= N_NODES) return;
  float v[C2];
  float d = den2[n] + 1e-16f;
  float m = -1e30f;
#pragma unroll
  for (int c = 0; c < C2; ++c) {
    v[c] = num2[(size_t)n*C2 + c] / d + ldmix(b2, c, mode);
    m = fmaxf(m, v[c]);
  }
  float s = 0.f;
#pragma unroll
  for (int c = 0; c < C2; ++c) s += __expf(v[c] - m);
  float lse = m + __logf(s);
  if (mode) {
    float* op = (float*)out;
#pragma unroll
    for (int c = 0; c < C2; ++c) op[(size_t)n*C2 + c] = v[c] - lse;
  } else {
    __hip_bfloat16* op = (__hip_bfloat16*)out;
#pragma unroll
    for (int c = 0; c < C2; ++c) op[(size_t)n*C2 + c] = __float2bfloat16(v[c] - lse);
  }
}

extern "C" void kernel_launch(void* const* d_in, const int* in_sizes, int n_in,
                              void* d_out, int out_size, void* d_ws, size_t ws_size,
                              hipStream_t stream)
{
  const void* x    = d_in[0];
  const int*  ei   = (const int*)d_in[1];
  const void* W1   = d_in[2];
  const void* as1w = d_in[3];
  const void* ad1w = d_in[4];
  const void* b1   = d_in[5];
  const void* W2   = d_in[6];
  const void* as2w = d_in[7];
  const void* ad2w = d_in[8];
  const void* b2   = d_in[9];

  // ---- workspace layout: [flag: 16 floats][12.0M floats] = 48 MB + 64 B ----
  int*   flag = (int*)d_ws;
  float* ws   = (float*)d_ws + 16;

  // region A [0, 3.2M floats): h1 as bf16 (6.4M elems); dead after edge1,
  // then aliased by layer-2 buffers:
  float* A    = ws;
  __bf16* h1b = (__bf16*)A;
  float* h2   = A;               // 0.7M
  float* as2  = A + 700000;      // 0.1M
  float* ad2  = A + 800000;      // 0.1M
  float* num2 = A + 900000;      // 0.7M
  float* den2 = A + 1600000;     // 0.1M  (ends 1.7M < 3.2M)

  size_t off = 3200000;
  float* as1  = ws + off; off += (size_t)N_NODES * NHEAD;  // 0.8M
  float* ad1  = ws + off; off += (size_t)N_NODES * NHEAD;  // 0.8M
  float* num1 = ws + off; off += (size_t)N_NODES * F1;     // 6.4M
  float* den1 = ws + off; off += (size_t)N_NODES * NHEAD;  // 0.8M -> 12.0M

  detect_kernel<<<1, 64, 0, stream>>>((const unsigned int*)x, flag);

  // zero num1+den1 (contiguous 7.2M floats)
  hipMemsetAsync(num1, 0, (size_t)N_NODES * (F1 + NHEAD) * sizeof(float), stream);

  gemm1_kernel<<<(N_NODES + 127) / 128, 256, 0, stream>>>(x, W1, h1b, flag);
  alpha1_kernel<<<(N_NODES * NHEAD + 255) / 256, 256, 0, stream>>>(h1b, as1w, ad1w, as1, ad1, flag);

  long long totE = (long long)N_EDGES + N_NODES;
  edge1_kernel<<<(unsigned)((totE + 3) / 4), 256, 0, stream>>>(ei, h1b, as1, ad1, num1, den1);
  finalize1_kernel<<<(unsigned)(((long long)N_NODES * F1 + 255) / 256), 256, 0, stream>>>(num1, den1, b1, flag);

  // h1 region dead -> zero num2+den2 (contiguous 0.8M floats)
  hipMemsetAsync(num2, 0, (size_t)N_NODES * (C2 + 1) * sizeof(float), stream);

  h2_kernel<<<(N_NODES + 255) / 256, 256, 0, stream>>>(num1, W2, as2w, ad2w, h2, as2, ad2, flag);
  edge2_kernel<<<(unsigned)((totE * 8 + 255) / 256), 256, 0, stream>>>(ei, h2, as2, ad2, num2, den2);
  out_kernel<<<(N_NODES + 255) / 256, 256, 0, stream>>>(num2, den2, b2, d_out, flag);
}

// Round 5
// 1170.479 us; speedup vs baseline: 1.5149x; 1.5149x over previous
//
#include <hip/hip_runtime.h>
#include <hip/hip_bf16.h>

#define N_NODES 100000
#define N_EDGES 3200000
#define F_IN 512
#define NHEAD 8
#define CH1 8
#define F1 64   // NHEAD*CH1
#define C2 7
#define NEG 0.2f

typedef __bf16 bf16x8 __attribute__((ext_vector_type(8)));
typedef float  f32x4  __attribute__((ext_vector_type(4)));
typedef unsigned int u32x4 __attribute__((ext_vector_type(4)));

union U4BF8 { u32x4 u; bf16x8 v; };

// load element i of a buffer whose dtype is f32 (mode=1) or bf16 (mode=0)
__device__ __forceinline__ float ldmix(const void* p, size_t i, int f32mode) {
  if (f32mode) return ((const float*)p)[i];
  union { unsigned short u; __bf16 b; } c;
  c.u = ((const unsigned short*)p)[i];
  return (float)c.b;
}

// ---------------- dtype detection: 1 wave -----------------------------------
__global__ void detect_kernel(const unsigned int* __restrict__ x, int* __restrict__ flag) {
  int lane = threadIdx.x & 63;
  unsigned int w = x[lane];
  union { unsigned short u; __bf16 b; } c;
  c.u = (unsigned short)(w & 0xFFFFu);
  float v = (float)c.b;
  bool big = !(fabsf(v) <= 1e6f);   // huge or NaN -> f32 data read as bf16
  unsigned long long m = __ballot(big);
  if (lane == 0) *flag = (m != 0ull) ? 1 : 0;
}

// ---------------- GEMM: h1[N,64] = x[N,512] @ W1[512,64]  (bf16 out) -------
__global__ __launch_bounds__(256) void gemm1_kernel(
    const void* __restrict__ x, const void* __restrict__ W1,
    __bf16* __restrict__ h1, const int* __restrict__ flag)
{
  const int mode = *flag;
  const int lane = threadIdx.x & 63;
  const int wave = threadIdx.x >> 6;
  const int c0   = wave * 16;
  const int m    = lane & 15;
  const int quad = lane >> 4;

  bf16x8 bfrag[16];
#pragma unroll
  for (int t = 0; t < 16; ++t) {
    bf16x8 tv;
#pragma unroll
    for (int j = 0; j < 8; ++j)
      tv[j] = (__bf16)ldmix(W1, (size_t)(32*t + quad*8 + j)*F1 + c0 + m, mode);
    bfrag[t] = tv;
  }

  const int rowBase = blockIdx.x * 128;
#pragma unroll 1
  for (int rt = 0; rt < 8; ++rt) {
    const int r0 = rowBase + rt*16;
    int rowA = r0 + m; if (rowA > N_NODES-1) rowA = N_NODES-1;
    f32x4 acc = {0.f, 0.f, 0.f, 0.f};
    if (mode) {
      const float* xpf = (const float*)x + (size_t)rowA * F_IN + quad*8;
#pragma unroll
      for (int t = 0; t < 16; ++t) {
        f32x4 lo = *(const f32x4*)(xpf + t*32);
        f32x4 hi = *(const f32x4*)(xpf + t*32 + 4);
        bf16x8 av;
#pragma unroll
        for (int j = 0; j < 4; ++j) { av[j] = (__bf16)lo[j]; av[4+j] = (__bf16)hi[j]; }
        acc = __builtin_amdgcn_mfma_f32_16x16x32_bf16(av, bfrag[t], acc, 0, 0, 0);
      }
    } else {
      const __bf16* xp = (const __bf16*)x + (size_t)rowA * F_IN + quad*8;
#pragma unroll
      for (int t = 0; t < 16; ++t) {
        U4BF8 a;
        a.u = *(const u32x4*)(xp + t*32);
        acc = __builtin_amdgcn_mfma_f32_16x16x32_bf16(a.v, bfrag[t], acc, 0, 0, 0);
      }
    }
#pragma unroll
    for (int j = 0; j < 4; ++j) {
      int row = r0 + quad*4 + j;
      if (row < N_NODES) h1[(size_t)row*F1 + c0 + m] = (__bf16)acc[j];
    }
  }
}

// ---------------- alpha_s1/alpha_d1 [N,8] ----------------------------------
__global__ __launch_bounds__(256) void alpha1_kernel(
    const __bf16* __restrict__ h1,
    const void* __restrict__ a_src, const void* __restrict__ a_dst,
    float* __restrict__ as, float* __restrict__ ad, const int* __restrict__ flag)
{
  const int mode = *flag;
  int i = blockIdx.x * 256 + threadIdx.x;   // n*8+h
  if (i >= N_NODES * NHEAD) return;
  int h = i & 7;
  const __bf16* hp = h1 + (size_t)(i >> 3) * F1 + h * CH1;
  float s = 0.f, d = 0.f;
#pragma unroll
  for (int c = 0; c < CH1; ++c) {
    float hv = (float)hp[c];
    s += hv * ldmix(a_src, h*CH1 + c, mode);
    d += hv * ldmix(a_dst, h*CH1 + c, mode);
  }
  as[i] = s; ad[i] = d;
}

// ---------------- CSR build --------------------------------------------------
__global__ __launch_bounds__(256) void count_kernel(
    const int* __restrict__ ei, int* __restrict__ deg)
{
  int e = blockIdx.x * 256 + threadIdx.x;
  if (e < N_EDGES) atomicAdd(deg + ei[N_EDGES + e], 1);
}

#define SCAN_BLK 1024
__global__ __launch_bounds__(SCAN_BLK) void scan1_kernel(
    const int* __restrict__ deg, int* __restrict__ off, int* __restrict__ blksum)
{
  __shared__ int s[SCAN_BLK];
  int tid = threadIdx.x;
  int gid = blockIdx.x * SCAN_BLK + tid;
  int v = (gid < N_NODES) ? deg[gid] : 0;
  s[tid] = v;
  __syncthreads();
#pragma unroll
  for (int o = 1; o < SCAN_BLK; o <<= 1) {
    int t = (tid >= o) ? s[tid - o] : 0;
    __syncthreads();
    s[tid] += t;
    __syncthreads();
  }
  if (gid < N_NODES) off[gid] = s[tid] - v;     // exclusive in block
  if (tid == SCAN_BLK-1) blksum[blockIdx.x] = s[tid];
}

__global__ void scan2_kernel(int* __restrict__ blk, int nb) {
  if (threadIdx.x == 0 && blockIdx.x == 0) {
    int run = 0;
    for (int b = 0; b < nb; ++b) { int v = blk[b]; blk[b] = run; run += v; }
  }
}

__global__ __launch_bounds__(256) void scan3_kernel(
    int* __restrict__ off, const int* __restrict__ blk, int* __restrict__ cursor)
{
  int gid = blockIdx.x * 256 + threadIdx.x;
  if (gid < N_NODES) {
    int o = off[gid] + blk[gid >> 10];
    off[gid] = o;
    cursor[gid] = o;
  }
  if (gid == 0) off[N_NODES] = N_EDGES;
}

__global__ __launch_bounds__(256) void fill_kernel(
    const int* __restrict__ ei, int* __restrict__ cursor, int* __restrict__ sorted)
{
  int e = blockIdx.x * 256 + threadIdx.x;
  if (e >= N_EDGES) return;
  int dst = ei[N_EDGES + e];
  int pos = atomicAdd(cursor + dst, 1);
  sorted[pos] = ei[e];   // src
}

// ---------------- layer-1 aggregate: one wave per dst (gather, no atomics) --
__global__ __launch_bounds__(256) void aggregate1_kernel(
    const int* __restrict__ off, const int* __restrict__ sorted,
    const __bf16* __restrict__ h1,
    const float* __restrict__ as, const float* __restrict__ ad,
    const void* __restrict__ b1, __bf16* __restrict__ out1,
    const int* __restrict__ flag)
{
  const int mode = *flag;
  const int lane = threadIdx.x & 63;
  int n = blockIdx.x * 4 + (threadIdx.x >> 6);
  if (n >= N_NODES) return;
  const int h = lane >> 3;
  const float ad_h = ad[n*NHEAD + h];

  // self-loop
  float e0 = as[n*NHEAD + h] + ad_h;
  e0 = e0 > 0.f ? e0 : NEG * e0;
  float w0 = __expf(e0);
  float acc = w0 * (float)h1[(size_t)n*F1 + lane];
  float den = w0;

  const int begin = off[n];
  const int cnt   = off[n+1] - begin;
  for (int base = 0; base < cnt; base += 64) {
    int idx = base + lane;
    int sv = (idx < cnt) ? sorted[begin + idx] : 0;
    int jmax = cnt - base; if (jmax > 64) jmax = 64;
    for (int j = 0; j < jmax; ++j) {
      int src = __shfl(sv, j);
      float e = as[src*NHEAD + h] + ad_h;
      e = e > 0.f ? e : NEG * e;
      float w = __expf(e);
      acc += w * (float)h1[(size_t)src*F1 + lane];
      den += w;
    }
  }
  out1[(size_t)n*F1 + lane] = (__bf16)(acc / den + ldmix(b1, lane, mode));
}

// ---------------- h2 = out1 @ W2 (padded to 8), alpha2 ----------------------
__global__ __launch_bounds__(256) void h2_kernel(
    const __bf16* __restrict__ out1, const void* __restrict__ W2,
    const void* __restrict__ a_src2, const void* __restrict__ a_dst2,
    float* __restrict__ h2p, float* __restrict__ as2, float* __restrict__ ad2,
    const int* __restrict__ flag)
{
  const int mode = *flag;
  __shared__ float W2f[F1*C2];
  __shared__ float asw[C2], adw[C2];
  int t = threadIdx.x;
  for (int i = t; i < F1*C2; i += 256) W2f[i] = ldmix(W2, i, mode);
  if (t < C2) { asw[t] = ldmix(a_src2, t, mode); adw[t] = ldmix(a_dst2, t, mode); }
  __syncthreads();
  int n = blockIdx.x * 256 + t;
  if (n >= N_NODES) return;
  float r[F1];
  const __bf16* row = out1 + (size_t)n * F1;
#pragma unroll
  for (int j = 0; j < F1; ++j) r[j] = (float)row[j];
  float s = 0.f, d = 0.f;
#pragma unroll
  for (int c = 0; c < C2; ++c) {
    float acc = 0.f;
#pragma unroll
    for (int j = 0; j < F1; ++j) acc += r[j] * W2f[j*C2 + c];
    h2p[(size_t)n*8 + c] = acc;
    s += acc * asw[c]; d += acc * adw[c];
  }
  h2p[(size_t)n*8 + 7] = 0.f;
  as2[n] = s; ad2[n] = d;
}

// ---------------- layer-2 aggregate: 8 dsts per wave, 8 lanes each ----------
__global__ __launch_bounds__(256) void aggregate2_kernel(
    const int* __restrict__ off, const int* __restrict__ sorted,
    const float* __restrict__ h2p,
    const float* __restrict__ as2, const float* __restrict__ ad2,
    float* __restrict__ logitsP)
{
  const int lane = threadIdx.x & 63;
  const int c    = lane & 7;
  long long wid  = (long long)blockIdx.x * 4 + (threadIdx.x >> 6);
  int n = (int)(wid * 8 + (lane >> 3));
  bool valid = (n < N_NODES);
  if (!valid) n = N_NODES - 1;
  const float ad_n = ad2[n];

  float e0 = as2[n] + ad_n;
  e0 = e0 > 0.f ? e0 : NEG * e0;
  float w0 = __expf(e0);
  float acc = w0 * h2p[(size_t)n*8 + c];   // c==7 slot is 0
  float den = w0;

  const int begin = off[n];
  const int cnt   = off[n+1] - begin;
  for (int base = 0; base < cnt; base += 8) {
    int idx = base + c;
    int sv = (idx < cnt) ? sorted[begin + idx] : 0;
#pragma unroll
    for (int j = 0; j < 8; ++j) {
      if (base + j < cnt) {
        int src = __shfl(sv, j, 8);
        float e = as2[src] + ad_n;
        e = e > 0.f ? e : NEG * e;
        float w = __expf(e);
        acc += w * h2p[(size_t)src*8 + c];
        den += w;
      }
    }
  }
  if (valid) logitsP[(size_t)n*8 + c] = acc / den;
}

// ---------------- final: + b2, log_softmax -> out ---------------------------
__global__ __launch_bounds__(256) void out_kernel(
    const float* __restrict__ logitsP, const void* __restrict__ b2,
    void* __restrict__ out, const int* __restrict__ flag)
{
  const int mode = *flag;
  int n = blockIdx.x * 256 + threadIdx.x;
  if (n >= N_NODES) return;
  float v[C2];
  float m = -1e30f;
#pragma unroll
  for (int c = 0; c < C2; ++c) {
    v[c] = logitsP[(size_t)n*8 + c] + ldmix(b2, c, mode);
    m = fmaxf(m, v[c]);
  }
  float s = 0.f;
#pragma unroll
  for (int c = 0; c < C2; ++c) s += __expf(v[c] - m);
  float lse = m + __logf(s);
  if (mode) {
    float* op = (float*)out;
#pragma unroll
    for (int c = 0; c < C2; ++c) op[(size_t)n*C2 + c] = v[c] - lse;
  } else {
    __hip_bfloat16* op = (__hip_bfloat16*)out;
#pragma unroll
    for (int c = 0; c < C2; ++c) op[(size_t)n*C2 + c] = __float2bfloat16(v[c] - lse);
  }
}

extern "C" void kernel_launch(void* const* d_in, const int* in_sizes, int n_in,
                              void* d_out, int out_size, void* d_ws, size_t ws_size,
                              hipStream_t stream)
{
  const void* x    = d_in[0];
  const int*  ei   = (const int*)d_in[1];
  const void* W1   = d_in[2];
  const void* as1w = d_in[3];
  const void* ad1w = d_in[4];
  const void* b1   = d_in[5];
  const void* W2   = d_in[6];
  const void* as2w = d_in[7];
  const void* ad2w = d_in[8];
  const void* b2   = d_in[9];

  // ---- workspace layout (float units), total 11.45M floats = 45.8 MB ----
  // NOTE: out1 = 100000*64 bf16 = 6.4M elems = 3.2M FLOAT slots (round-4 bug:
  // was counted as 1.6M, overlapping the CSR arrays -> memory fault).
  int*   flag = (int*)d_ws;
  float* ws   = (float*)d_ws + 16;

  float*  A      = ws;                      // region A: [0, 3.2M)
  __bf16* h1b    = (__bf16*)A;              // 6.4M bf16 (dead after aggregate1)
  float*  h2p    = A;                       // 0.8M (aliases dead h1b)
  float*  as2    = A + 800000;              // 0.1M
  float*  ad2    = A + 900000;              // 0.1M
  float*  logitsP= A + 1000000;             // 0.8M (ends 1.8M < 3.2M)

  float*  as1    = ws + 3200000;            // [3.2M, 4.0M)
  float*  ad1    = ws + 4000000;            // [4.0M, 4.8M)
  __bf16* out1   = (__bf16*)(ws + 4800000); // [4.8M, 8.0M) : 6.4M bf16
  int*    deg    = (int*)(ws + 8000000);    // [8.0M, 8.1M) (deg, then cursor)
  int*    off    = (int*)(ws + 8100000);    // [8.1M, 8.2M+1)
  int*    blk    = (int*)(ws + 8210000);    // 1024 ints
  int*    sorted = (int*)(ws + 8250000);    // [8.25M, 11.45M) : 3.2M ints

  detect_kernel<<<1, 64, 0, stream>>>((const unsigned int*)x, flag);
  hipMemsetAsync(deg, 0, (size_t)N_NODES * sizeof(int), stream);

  gemm1_kernel<<<(N_NODES + 127) / 128, 256, 0, stream>>>(x, W1, h1b, flag);
  alpha1_kernel<<<(N_NODES * NHEAD + 255) / 256, 256, 0, stream>>>(h1b, as1w, ad1w, as1, ad1, flag);

  // CSR build (dst-sorted adjacency, used by both layers)
  count_kernel<<<(N_EDGES + 255) / 256, 256, 0, stream>>>(ei, deg);
  int nb = (N_NODES + SCAN_BLK - 1) / SCAN_BLK;   // 98
  scan1_kernel<<<nb, SCAN_BLK, 0, stream>>>(deg, off, blk);
  scan2_kernel<<<1, 64, 0, stream>>>(blk, nb);
  scan3_kernel<<<(N_NODES + 255) / 256, 256, 0, stream>>>(off, blk, deg /*cursor*/);
  fill_kernel<<<(N_EDGES + 255) / 256, 256, 0, stream>>>(ei, deg /*cursor*/, sorted);

  aggregate1_kernel<<<(N_NODES + 3) / 4, 256, 0, stream>>>(
      off, sorted, h1b, as1, ad1, b1, out1, flag);

  h2_kernel<<<(N_NODES + 255) / 256, 256, 0, stream>>>(out1, W2, as2w, ad2w, h2p, as2, ad2, flag);

  aggregate2_kernel<<<(N_NODES/8 + 3) / 4 + 1, 256, 0, stream>>>(
      off, sorted, h2p, as2, ad2, logitsP);

  out_kernel<<<(N_NODES + 255) / 256, 256, 0, stream>>>(logitsP, b2, d_out, flag);
}

// Round 6
// 885.664 us; speedup vs baseline: 2.0021x; 1.3216x over previous
//
#include <hip/hip_runtime.h>
#include <hip/hip_bf16.h>

#define N_NODES 100000
#define N_EDGES 3200000
#define F_IN 512
#define NHEAD 8
#define CH1 8
#define F1 64   // NHEAD*CH1
#define C2 7
#define NEG 0.2f
#define NBUCK 391   // dst>>8 : 99999>>8 = 390

typedef __bf16 bf16x8 __attribute__((ext_vector_type(8)));
typedef float  f32x4  __attribute__((ext_vector_type(4)));
typedef unsigned int u32x4 __attribute__((ext_vector_type(4)));

union U4BF8 { u32x4 u; bf16x8 v; };

// load element i of a buffer whose dtype is f32 (mode=1) or bf16 (mode=0)
__device__ __forceinline__ float ldmix(const void* p, size_t i, int f32mode) {
  if (f32mode) return ((const float*)p)[i];
  union { unsigned short u; __bf16 b; } c;
  c.u = ((const unsigned short*)p)[i];
  return (float)c.b;
}

// ---------------- dtype detection: 1 wave -----------------------------------
__global__ void detect_kernel(const unsigned int* __restrict__ x, int* __restrict__ flag) {
  int lane = threadIdx.x & 63;
  unsigned int w = x[lane];
  union { unsigned short u; __bf16 b; } c;
  c.u = (unsigned short)(w & 0xFFFFu);
  float v = (float)c.b;
  bool big = !(fabsf(v) <= 1e6f);   // huge or NaN -> f32 data read as bf16
  unsigned long long m = __ballot(big);
  if (lane == 0) *flag = (m != 0ull) ? 1 : 0;
}

// ---------------- GEMM: h1[N,64] = x[N,512] @ W1[512,64]  (bf16 out) -------
__global__ __launch_bounds__(256) void gemm1_kernel(
    const void* __restrict__ x, const void* __restrict__ W1,
    __bf16* __restrict__ h1, const int* __restrict__ flag)
{
  const int mode = *flag;
  const int lane = threadIdx.x & 63;
  const int wave = threadIdx.x >> 6;
  const int c0   = wave * 16;
  const int m    = lane & 15;
  const int quad = lane >> 4;

  bf16x8 bfrag[16];
#pragma unroll
  for (int t = 0; t < 16; ++t) {
    bf16x8 tv;
#pragma unroll
    for (int j = 0; j < 8; ++j)
      tv[j] = (__bf16)ldmix(W1, (size_t)(32*t + quad*8 + j)*F1 + c0 + m, mode);
    bfrag[t] = tv;
  }

  const int rowBase = blockIdx.x * 128;
#pragma unroll 1
  for (int rt = 0; rt < 8; ++rt) {
    const int r0 = rowBase + rt*16;
    int rowA = r0 + m; if (rowA > N_NODES-1) rowA = N_NODES-1;
    f32x4 acc = {0.f, 0.f, 0.f, 0.f};
    if (mode) {
      const float* xpf = (const float*)x + (size_t)rowA * F_IN + quad*8;
#pragma unroll
      for (int t = 0; t < 16; ++t) {
        f32x4 lo = *(const f32x4*)(xpf + t*32);
        f32x4 hi = *(const f32x4*)(xpf + t*32 + 4);
        bf16x8 av;
#pragma unroll
        for (int j = 0; j < 4; ++j) { av[j] = (__bf16)lo[j]; av[4+j] = (__bf16)hi[j]; }
        acc = __builtin_amdgcn_mfma_f32_16x16x32_bf16(av, bfrag[t], acc, 0, 0, 0);
      }
    } else {
      const __bf16* xp = (const __bf16*)x + (size_t)rowA * F_IN + quad*8;
#pragma unroll
      for (int t = 0; t < 16; ++t) {
        U4BF8 a;
        a.u = *(const u32x4*)(xp + t*32);
        acc = __builtin_amdgcn_mfma_f32_16x16x32_bf16(a.v, bfrag[t], acc, 0, 0, 0);
      }
    }
#pragma unroll
    for (int j = 0; j < 4; ++j) {
      int row = r0 + quad*4 + j;
      if (row < N_NODES) h1[(size_t)row*F1 + c0 + m] = (__bf16)acc[j];
    }
  }
}

// ---------------- alpha_s1/alpha_d1 [N,8] ----------------------------------
__global__ __launch_bounds__(256) void alpha1_kernel(
    const __bf16* __restrict__ h1,
    const void* __restrict__ a_src, const void* __restrict__ a_dst,
    float* __restrict__ as, float* __restrict__ ad, const int* __restrict__ flag)
{
  const int mode = *flag;
  int i = blockIdx.x * 256 + threadIdx.x;   // n*8+h
  if (i >= N_NODES * NHEAD) return;
  int h = i & 7;
  const __bf16* hp = h1 + (size_t)(i >> 3) * F1 + h * CH1;
  float s = 0.f, d = 0.f;
#pragma unroll
  for (int c = 0; c < CH1; ++c) {
    float hv = (float)hp[c];
    s += hv * ldmix(a_src, h*CH1 + c, mode);
    d += hv * ldmix(a_dst, h*CH1 + c, mode);
  }
  as[i] = s; ad[i] = d;
}

// ---------------- CSR build, two-level binned -------------------------------
// Phase A: bucket histogram (LDS-aggregated)
__global__ __launch_bounds__(256) void buckhist_kernel(
    const int* __restrict__ ei, int* __restrict__ bh)
{
  __shared__ int h[NBUCK];
  for (int i = threadIdx.x; i < NBUCK; i += 256) h[i] = 0;
  __syncthreads();
  int start = blockIdx.x * 4096;
  for (int i = threadIdx.x; i < 4096; i += 256) {
    int e = start + i;
    if (e < N_EDGES) atomicAdd(&h[ei[N_EDGES + e] >> 8], 1);
  }
  __syncthreads();
  for (int i = threadIdx.x; i < NBUCK; i += 256) {
    int c = h[i];
    if (c) atomicAdd(&bh[i], c);
  }
}

// Phase B-scan: exclusive scan of 391 bucket counts -> bases + cursors
__global__ __launch_bounds__(512) void buckscan_kernel(
    const int* __restrict__ bh, int* __restrict__ bb, int* __restrict__ bcur)
{
  __shared__ int s[512];
  int t = threadIdx.x;
  int v = (t < NBUCK) ? bh[t] : 0;
  s[t] = v;
  __syncthreads();
#pragma unroll
  for (int o = 1; o < 512; o <<= 1) {
    int u = (t >= o) ? s[t - o] : 0;
    __syncthreads();
    s[t] += u;
    __syncthreads();
  }
  if (t < NBUCK) { bb[t] = s[t] - v; bcur[t] = s[t] - v; }
  if (t == NBUCK - 1) bb[NBUCK] = s[t];
}

// Phase B: scatter packed (src<<8 | dst&255) into bucket-ordered `pairs`.
// Per-block LDS histogram -> one global range-claim per bucket -> dense writes.
#define CHB 16384
__global__ __launch_bounds__(256) void buckscatter_kernel(
    const int* __restrict__ ei, int* __restrict__ bcur, int* __restrict__ pairs)
{
  __shared__ int h[NBUCK];
  __shared__ int base[NBUCK];
  for (int i = threadIdx.x; i < NBUCK; i += 256) h[i] = 0;
  __syncthreads();
  int start = blockIdx.x * CHB;
  for (int i = threadIdx.x; i < CHB; i += 256) {
    int e = start + i;
    if (e < N_EDGES) atomicAdd(&h[ei[N_EDGES + e] >> 8], 1);
  }
  __syncthreads();
  for (int i = threadIdx.x; i < NBUCK; i += 256) {
    int c = h[i];
    base[i] = c ? atomicAdd(&bcur[i], c) : 0;
    h[i] = 0;
  }
  __syncthreads();
  for (int i = threadIdx.x; i < CHB; i += 256) {
    int e = start + i;
    if (e < N_EDGES) {
      int dst = ei[N_EDGES + e];
      int src = ei[e];
      int b = dst >> 8;
      int pos = base[b] + atomicAdd(&h[b], 1);
      pairs[pos] = (src << 8) | (dst & 255);
    }
  }
}

// Phase C: one block per bucket: LDS per-dst hist + scan -> off[] AND sorted[]
__global__ __launch_bounds__(256) void csrbuild_kernel(
    const int* __restrict__ bb, const int* __restrict__ pairs,
    int* __restrict__ off, int* __restrict__ sorted)
{
  __shared__ int cnt[256];
  __shared__ int scan[256];
  int b = blockIdx.x;
  int lo = bb[b], hi = bb[b+1];
  int t = threadIdx.x;
  cnt[t] = 0;
  __syncthreads();
  for (int i = lo + t; i < hi; i += 256)
    atomicAdd(&cnt[pairs[i] & 255], 1);
  __syncthreads();
  int v = cnt[t];
  scan[t] = v;
  __syncthreads();
#pragma unroll
  for (int o = 1; o < 256; o <<= 1) {
    int u = (t >= o) ? scan[t - o] : 0;
    __syncthreads();
    scan[t] += u;
    __syncthreads();
  }
  int excl = scan[t] - v;
  int node = b * 256 + t;
  if (node < N_NODES) off[node] = lo + excl;
  if (b == 0 && t == 0) off[N_NODES] = N_EDGES;
  __syncthreads();
  cnt[t] = excl;   // cursor
  __syncthreads();
  for (int i = lo + t; i < hi; i += 256) {
    int p = pairs[i];
    int w = lo + atomicAdd(&cnt[p & 255], 1);
    sorted[w] = p >> 8;
  }
}

// ---------------- layer-1 aggregate: one wave per dst (gather, no atomics) --
__global__ __launch_bounds__(256) void aggregate1_kernel(
    const int* __restrict__ off, const int* __restrict__ sorted,
    const __bf16* __restrict__ h1,
    const float* __restrict__ as, const float* __restrict__ ad,
    const void* __restrict__ b1, __bf16* __restrict__ out1,
    const int* __restrict__ flag)
{
  const int mode = *flag;
  const int lane = threadIdx.x & 63;
  int n = blockIdx.x * 4 + (threadIdx.x >> 6);
  if (n >= N_NODES) return;
  const int h = lane >> 3;
  const float ad_h = ad[n*NHEAD + h];

  // self-loop
  float e0 = as[n*NHEAD + h] + ad_h;
  e0 = e0 > 0.f ? e0 : NEG * e0;
  float w0 = __expf(e0);
  float acc = w0 * (float)h1[(size_t)n*F1 + lane];
  float den = w0;

  const int begin = off[n];
  const int cnt   = off[n+1] - begin;
  for (int base = 0; base < cnt; base += 64) {
    int idx = base + lane;
    int sv = (idx < cnt) ? sorted[begin + idx] : 0;
    int jmax = cnt - base; if (jmax > 64) jmax = 64;
    for (int j = 0; j < jmax; ++j) {
      int src = __shfl(sv, j);
      float e = as[src*NHEAD + h] + ad_h;
      e = e > 0.f ? e : NEG * e;
      float w = __expf(e);
      acc += w * (float)h1[(size_t)src*F1 + lane];
      den += w;
    }
  }
  out1[(size_t)n*F1 + lane] = (__bf16)(acc / den + ldmix(b1, lane, mode));
}

// ---------------- h2 = out1 @ W2 (padded to 8), alpha2 ----------------------
__global__ __launch_bounds__(256) void h2_kernel(
    const __bf16* __restrict__ out1, const void* __restrict__ W2,
    const void* __restrict__ a_src2, const void* __restrict__ a_dst2,
    float* __restrict__ h2p, float* __restrict__ as2, float* __restrict__ ad2,
    const int* __restrict__ flag)
{
  const int mode = *flag;
  __shared__ float W2f[F1*C2];
  __shared__ float asw[C2], adw[C2];
  int t = threadIdx.x;
  for (int i = t; i < F1*C2; i += 256) W2f[i] = ldmix(W2, i, mode);
  if (t < C2) { asw[t] = ldmix(a_src2, t, mode); adw[t] = ldmix(a_dst2, t, mode); }
  __syncthreads();
  int n = blockIdx.x * 256 + t;
  if (n >= N_NODES) return;
  float r[F1];
  const __bf16* row = out1 + (size_t)n * F1;
#pragma unroll
  for (int j = 0; j < F1; ++j) r[j] = (float)row[j];
  float s = 0.f, d = 0.f;
#pragma unroll
  for (int c = 0; c < C2; ++c) {
    float acc = 0.f;
#pragma unroll
    for (int j = 0; j < F1; ++j) acc += r[j] * W2f[j*C2 + c];
    h2p[(size_t)n*8 + c] = acc;
    s += acc * asw[c]; d += acc * adw[c];
  }
  h2p[(size_t)n*8 + 7] = 0.f;
  as2[n] = s; ad2[n] = d;
}

// ---------------- layer-2 aggregate: 8 dsts per wave, 8 lanes each ----------
__global__ __launch_bounds__(256) void aggregate2_kernel(
    const int* __restrict__ off, const int* __restrict__ sorted,
    const float* __restrict__ h2p,
    const float* __restrict__ as2, const float* __restrict__ ad2,
    float* __restrict__ logitsP)
{
  const int lane = threadIdx.x & 63;
  const int c    = lane & 7;
  long long wid  = (long long)blockIdx.x * 4 + (threadIdx.x >> 6);
  int n = (int)(wid * 8 + (lane >> 3));
  bool valid = (n < N_NODES);
  if (!valid) n = N_NODES - 1;
  const float ad_n = ad2[n];

  float e0 = as2[n] + ad_n;
  e0 = e0 > 0.f ? e0 : NEG * e0;
  float w0 = __expf(e0);
  float acc = w0 * h2p[(size_t)n*8 + c];   // c==7 slot is 0
  float den = w0;

  const int begin = off[n];
  const int cnt   = off[n+1] - begin;
  for (int base = 0; base < cnt; base += 8) {
    int idx = base + c;
    int sv = (idx < cnt) ? sorted[begin + idx] : 0;
#pragma unroll
    for (int j = 0; j < 8; ++j) {
      if (base + j < cnt) {
        int src = __shfl(sv, j, 8);
        float e = as2[src] + ad_n;
        e = e > 0.f ? e : NEG * e;
        float w = __expf(e);
        acc += w * h2p[(size_t)src*8 + c];
        den += w;
      }
    }
  }
  if (valid) logitsP[(size_t)n*8 + c] = acc / den;
}

// ---------------- final: + b2, log_softmax -> out ---------------------------
__global__ __launch_bounds__(256) void out_kernel(
    const float* __restrict__ logitsP, const void* __restrict__ b2,
    void* __restrict__ out, const int* __restrict__ flag)
{
  const int mode = *flag;
  int n = blockIdx.x * 256 + threadIdx.x;
  if (n >= N_NODES) return;
  float v[C2];
  float m = -1e30f;
#pragma unroll
  for (int c = 0; c < C2; ++c) {
    v[c] = logitsP[(size_t)n*8 + c] + ldmix(b2, c, mode);
    m = fmaxf(m, v[c]);
  }
  float s = 0.f;
#pragma unroll
  for (int c = 0; c < C2; ++c) s += __expf(v[c] - m);
  float lse = m + __logf(s);
  if (mode) {
    float* op = (float*)out;
#pragma unroll
    for (int c = 0; c < C2; ++c) op[(size_t)n*C2 + c] = v[c] - lse;
  } else {
    __hip_bfloat16* op = (__hip_bfloat16*)out;
#pragma unroll
    for (int c = 0; c < C2; ++c) op[(size_t)n*C2 + c] = __float2bfloat16(v[c] - lse);
  }
}

extern "C" void kernel_launch(void* const* d_in, const int* in_sizes, int n_in,
                              void* d_out, int out_size, void* d_ws, size_t ws_size,
                              hipStream_t stream)
{
  const void* x    = d_in[0];
  const int*  ei   = (const int*)d_in[1];
  const void* W1   = d_in[2];
  const void* as1w = d_in[3];
  const void* ad1w = d_in[4];
  const void* b1   = d_in[5];
  const void* W2   = d_in[6];
  const void* as2w = d_in[7];
  const void* ad2w = d_in[8];
  const void* b2   = d_in[9];

  // ---- workspace layout (float units), total 11.45M floats = 45.8 MB ----
  int*   flag = (int*)d_ws;
  float* ws   = (float*)d_ws + 16;

  float*  A      = ws;                      // region A: [0, 3.2M)
  __bf16* h1b    = (__bf16*)A;              // 6.4M bf16 (dead after aggregate1)
  float*  h2p    = A;                       // 0.8M (aliases dead h1b)
  float*  as2    = A + 800000;              // 0.1M
  float*  ad2    = A + 900000;              // 0.1M
  float*  logitsP= A + 1000000;             // 0.8M (ends 1.8M < 3.2M)

  float*  as1    = ws + 3200000;            // [3.2M, 4.0M)
  float*  ad1    = ws + 4000000;            // [4.0M, 4.8M)
  __bf16* out1   = (__bf16*)(ws + 4800000); // [4.8M, 8.0M) : 6.4M bf16
  int*    pairs  = (int*)(ws + 4800000);    // 3.2M ints, aliases out1 (dead
                                            //   until aggregate1 writes it;
                                            //   pairs dead after csrbuild)
  int*    off    = (int*)(ws + 8000000);    // 100001 ints
  int*    bh     = (int*)(ws + 8110000);    // 391 ints (bucket hist)
  int*    bb     = (int*)(ws + 8112000);    // 392 ints (bucket base)
  int*    bcur   = (int*)(ws + 8114000);    // 391 ints (bucket cursor)
  int*    sorted = (int*)(ws + 8250000);    // [8.25M, 11.45M) : 3.2M ints

  detect_kernel<<<1, 64, 0, stream>>>((const unsigned int*)x, flag);
  hipMemsetAsync(bh, 0, NBUCK * sizeof(int), stream);

  gemm1_kernel<<<(N_NODES + 127) / 128, 256, 0, stream>>>(x, W1, h1b, flag);
  alpha1_kernel<<<(N_NODES * NHEAD + 255) / 256, 256, 0, stream>>>(h1b, as1w, ad1w, as1, ad1, flag);

  // CSR build (two-level binned; dst-major order == CSR order)
  buckhist_kernel<<<(N_EDGES + 4095) / 4096, 256, 0, stream>>>(ei, bh);
  buckscan_kernel<<<1, 512, 0, stream>>>(bh, bb, bcur);
  buckscatter_kernel<<<(N_EDGES + CHB - 1) / CHB, 256, 0, stream>>>(ei, bcur, pairs);
  csrbuild_kernel<<<NBUCK, 256, 0, stream>>>(bb, pairs, off, sorted);

  aggregate1_kernel<<<(N_NODES + 3) / 4, 256, 0, stream>>>(
      off, sorted, h1b, as1, ad1, b1, out1, flag);

  h2_kernel<<<(N_NODES + 255) / 256, 256, 0, stream>>>(out1, W2, as2w, ad2w, h2p, as2, ad2, flag);

  aggregate2_kernel<<<(N_NODES/8 + 3) / 4 + 1, 256, 0, stream>>>(
      off, sorted, h2p, as2, ad2, logitsP);

  out_kernel<<<(N_NODES + 255) / 256, 256, 0, stream>>>(logitsP, b2, d_out, flag);
}